// Round 1
// baseline (809.873 us; speedup 1.0000x reference)
//
#include <hip/hip_runtime.h>

#define EPS_DIR 1e-15f
#define EPS_W   1e-5f
#define NEAR_MIN 0.05f

// One THREAD per ray (was: one wave per ray). rocprof showed the wave-per-ray
// kernel is VALU-bound (VALUBusy 78%, HBM 21% of peak): ~450 wave-inst/ray
// from shfl-scan, exec-masked scatter loop, and 64-lane-redundant math.
// Thread-per-ray does the O(T) sum + O(T+n) two-pointer inverse-CDF merge
// serially per lane: ~60 wave-inst/ray, every lane useful. Loads are per-lane
// row streams (stride 508B across lanes); each 64B line serves 16 consecutive
// scalar loads, and the sum pass warms L2/L3 for the merge pass.
__global__ __launch_bounds__(256) void nerf_sample_pdf_kernel(
    const float* __restrict__ rays_o,
    const float* __restrict__ rays_d,
    const float* __restrict__ weights,
    const int*   __restrict__ bound_p,
    float*       __restrict__ out,
    int R, int Tm1, int n)
{
    const int ray = blockIdx.x * blockDim.x + threadIdx.x;
    if (ray >= R) return;

    // ---- near/far cube intersection (loads issued early) ----
    const float b = (float)bound_p[0];
    float nearv = -3.4e38f, farv = 3.4e38f;
#pragma unroll
    for (int k = 0; k < 3; ++k) {
        float o = rays_o[(size_t)ray * 3 + k];
        float d = rays_d[(size_t)ray * 3 + k] + EPS_DIR;
        float r = __builtin_amdgcn_rcpf(d);
        float t0 = (-b - o) * r;
        float t1 = ( b - o) * r;
        nearv = fmaxf(nearv, fminf(t0, t1));
        farv  = fminf(farv,  fmaxf(t0, t1));
    }
    nearv = fmaxf(nearv, NEAR_MIN);
    const float scale = (farv - nearv) * __builtin_amdgcn_rcpf((float)Tm1);

    const float* __restrict__ wrow = weights + (size_t)ray * Tm1;

    // ---- phase 1: total weight (4 accumulators so loads batch) ----
    float s0 = 0.f, s1 = 0.f, s2 = 0.f, s3 = 0.f;
    int i = 0;
    for (; i + 4 <= Tm1; i += 4) {
        s0 += wrow[i + 0];
        s1 += wrow[i + 1];
        s2 += wrow[i + 2];
        s3 += wrow[i + 3];
    }
    for (; i < Tm1; ++i) s0 += wrow[i];
    const float total = ((s0 + s1) + (s2 + s3)) + (float)Tm1 * EPS_W;
    const float rtot  = __builtin_amdgcn_rcpf(total);

    // ---- phase 2: two-pointer inverse-CDF merge ----
    // searchsorted(side='right'): sample u lives in interval idx while
    // cdf[idx] <= u < cdf[idx+1]; advance while cdf[idx+1] <= u.
    const float inv_n = 1.0f / (float)n;   // n=128 -> exact, u_j=(j+0.5)/n exact
    float u    = 0.5f * inv_n;
    int   idx  = 0;
    float c_lo = 0.0f;
    float c_hi = (wrow[0] + EPS_W) * rtot;
    float wnext = (Tm1 > 1) ? wrow[1] : 0.0f;  // raw prefetch of wrow[idx+1]
    const int last = Tm1 - 1;

    float* __restrict__ orow = out + (size_t)ray * n;

    const int ng = n >> 2;                 // emit 4 samples per float4 store
    for (int g = 0; g < ng; ++g) {
        float z0, z1, z2, z3;
#pragma unroll
        for (int s = 0; s < 4; ++s) {
            while (c_hi <= u && idx < last) {
                ++idx;
                c_lo = c_hi;
                const float wn = wnext + EPS_W;
                wnext = wrow[(idx + 1 < Tm1) ? (idx + 1) : last];
                c_hi  = c_lo + wn * rtot;
            }
            const float d  = c_hi - c_lo;
            const float rd = (d < EPS_W) ? 1.0f : __builtin_amdgcn_rcpf(d);
            const float t  = (u - c_lo) * rd;
            const float z  = fmaf(scale, (float)idx + t, nearv);
            if      (s == 0) z0 = z;
            else if (s == 1) z1 = z;
            else if (s == 2) z2 = z;
            else             z3 = z;
            u += inv_n;
        }
        *reinterpret_cast<float4*>(orow + 4 * g) = make_float4(z0, z1, z2, z3);
    }
    for (int j = ng * 4; j < n; ++j) {     // generic tail (n=128: never runs)
        while (c_hi <= u && idx < last) {
            ++idx;
            c_lo = c_hi;
            const float wn = wnext + EPS_W;
            wnext = wrow[(idx + 1 < Tm1) ? (idx + 1) : last];
            c_hi  = c_lo + wn * rtot;
        }
        const float d  = c_hi - c_lo;
        const float rd = (d < EPS_W) ? 1.0f : __builtin_amdgcn_rcpf(d);
        orow[j] = fmaf(scale, (float)idx + (u - c_lo) * rd, nearv);
        u += inv_n;
    }
}

extern "C" void kernel_launch(void* const* d_in, const int* in_sizes, int n_in,
                              void* d_out, int out_size, void* d_ws, size_t ws_size,
                              hipStream_t stream) {
    const float* rays_o  = (const float*)d_in[0];
    const float* rays_d  = (const float*)d_in[1];
    const float* weights = (const float*)d_in[2];
    const int*   bound_p = (const int*)d_in[3];
    float*       out     = (float*)d_out;

    const int R   = in_sizes[0] / 3;       // 262144 rays
    const int Tm1 = in_sizes[2] / R;       // 127 weights per ray
    const int n   = out_size / R;          // 128 samples per ray

    dim3 grid((R + 255) / 256), block(256);
    nerf_sample_pdf_kernel<<<grid, block, 0, stream>>>(
        rays_o, rays_d, weights, bound_p, out, R, Tm1, n);
}

// Round 3
// 295.358 us; speedup vs baseline: 2.7420x; 2.7420x over previous
//
#include <hip/hip_runtime.h>

#define EPS_DIR 1e-15f
#define EPS_W   1e-5f
#define NEAR_MIN 0.05f

// Wave-per-ray, GATHER formulation.
// Round-1 post-mortem: thread-per-ray blew FETCH_SIZE up 12x (64 distinct
// cache lines per wave-load; L1/L2 thrash at 508B lane stride) -> 647us.
// Round-0 wave-per-ray had perfect memory behavior but was VALU-bound
// (78% busy, ~450 wave-inst/ray) in the divergent ownership-scatter loop.
// This kernel keeps wave-per-ray coalescing and replaces the scatter with a
// CONVERGENT per-lane binary search over a 128-entry CDF staged in LDS:
// each lane does exactly 7 lookup steps for each of its 2 owned samples
// (u = (2*lane+{0.5,1.5})/n), uniform control flow, and the store becomes
// one coalesced float2 per lane (512B contiguous per wave).
__global__ __launch_bounds__(256) void nerf_sample_pdf_kernel(
    const float* __restrict__ rays_o,
    const float* __restrict__ rays_d,
    const float* __restrict__ weights,
    const int*   __restrict__ bound_p,
    float*       __restrict__ out,
    int R, int Tm1, int n)
{
    const int lane = threadIdx.x & 63;
    const int wid  = threadIdx.x >> 6;
    int ray = blockIdx.x * 4 + wid;
    const bool valid = (ray < R);
    if (!valid) ray = R - 1;            // clamp: loads safe, stores guarded

    __shared__ float cdf_s[4][132];     // 128-entry CDF per wave (+pad)
    float* __restrict__ cdf = cdf_s[wid];

    // ---- load 2 weights per lane (coalesced stride-2 within 508B row) ----
    const float* __restrict__ wrow = weights + (size_t)ray * Tm1;
    const int i0 = 2 * lane, i1 = 2 * lane + 1;
    float w0 = (i0 < Tm1) ? (wrow[i0] + EPS_W) : 0.0f;
    float w1 = (i1 < Tm1) ? (wrow[i1] + EPS_W) : 0.0f;

    // ---- wave inclusive scan of pair sums ----
    float S = w0 + w1;
#pragma unroll
    for (int off = 1; off < 64; off <<= 1) {
        float y = __shfl_up(S, off, 64);
        if (lane >= off) S += y;
    }
    const float total = __shfl(S, 63, 64);
    const float rinv  = __builtin_amdgcn_rcpf(total);
    float prevS = __shfl_up(S, 1, 64);
    if (lane == 0) prevS = 0.0f;

    // cdf[k] = (sum of first k weights)/total, cdf[0] = 0 exactly.
    // Lane l writes entries 2l (prefix before its pair) and 2l+1.
    cdf[i0] = prevS * rinv;
    cdf[i1] = (prevS + w0) * rinv;
    __syncthreads();                    // LDS visibility (single barrier)

    // ---- near/far cube intersection (wave-uniform) ----
    const float b = (float)bound_p[0];
    float nearv = -3.4e38f, farv = 3.4e38f;
#pragma unroll
    for (int k = 0; k < 3; ++k) {
        float o = rays_o[(size_t)ray * 3 + k];
        float d = rays_d[(size_t)ray * 3 + k] + EPS_DIR;
        float r = __builtin_amdgcn_rcpf(d);
        float t0 = (-b - o) * r;
        float t1 = ( b - o) * r;
        nearv = fmaxf(nearv, fminf(t0, t1));
        farv  = fminf(farv,  fmaxf(t0, t1));
    }
    nearv = fmaxf(nearv, NEAR_MIN);
    const float scale = (farv - nearv) * __builtin_amdgcn_rcpf((float)Tm1);
    const float inv_n = 1.0f / (float)n;

    float* __restrict__ orow = out + (size_t)ray * n;

    // ---- 2 samples per lane: convergent binary search (searchsorted-right)
    for (int base = 0; base < n; base += 128) {
        const int j = base + 2 * lane;
        if (j >= n) break;
        const float u0 = ((float)j + 0.5f) * inv_n;   // exact for n=128
        const float u1 = u0 + inv_n;

        // largest p with cdf[p] <= u  (binary lifting over 128 entries;
        // p+step never exceeds 127). Track v = cdf[p] for free.
        int   p0 = 0,   p1 = 0;
        float v0 = 0.f, v1 = 0.f;
#pragma unroll
        for (int step = 64; step >= 1; step >>= 1) {
            const float c0 = cdf[p0 + step];
            const float c1 = cdf[p1 + step];
            if (c0 <= u0) { p0 += step; v0 = c0; }
            if (c1 <= u1) { p1 += step; v1 = c1; }
        }
        // p == below == inds-1 ; above = min(inds, Tm1)
        const int a0 = (p0 < Tm1) ? p0 + 1 : Tm1;
        const int a1 = (p1 < Tm1) ? p1 + 1 : Tm1;
        const float h0 = cdf[a0];
        const float h1 = cdf[a1];
        const float d0 = h0 - v0;
        const float d1 = h1 - v1;
        const float t0 = (u0 - v0) * ((d0 < EPS_W) ? 1.0f : __builtin_amdgcn_rcpf(d0));
        const float t1 = (u1 - v1) * ((d1 < EPS_W) ? 1.0f : __builtin_amdgcn_rcpf(d1));
        // z = bin_lo + t*(bin_hi - bin_lo); bin_k = near + k*scale
        const float z0 = fmaf(t0, (float)(a0 - p0) * scale, fmaf((float)p0, scale, nearv));
        const float z1 = fmaf(t1, (float)(a1 - p1) * scale, fmaf((float)p1, scale, nearv));

        if (valid) {
            if (j + 1 < n) {
                *reinterpret_cast<float2*>(orow + j) = make_float2(z0, z1);
            } else {
                orow[j] = z0;           // odd-n tail (n=128: never runs)
            }
        }
    }
}

extern "C" void kernel_launch(void* const* d_in, const int* in_sizes, int n_in,
                              void* d_out, int out_size, void* d_ws, size_t ws_size,
                              hipStream_t stream) {
    const float* rays_o  = (const float*)d_in[0];
    const float* rays_d  = (const float*)d_in[1];
    const float* weights = (const float*)d_in[2];
    const int*   bound_p = (const int*)d_in[3];
    float*       out     = (float*)d_out;

    const int R   = in_sizes[0] / 3;       // 262144 rays
    const int Tm1 = in_sizes[2] / R;       // 127 weights per ray
    const int n   = out_size / R;          // 128 samples per ray

    dim3 grid((R + 3) / 4), block(256);    // 4 waves/block = 4 rays/block
    nerf_sample_pdf_kernel<<<grid, block, 0, stream>>>(
        rays_o, rays_d, weights, bound_p, out, R, Tm1, n);
}

// Round 5
// 258.149 us; speedup vs baseline: 3.1372x; 1.1441x over previous
//
#include <hip/hip_runtime.h>

#define EPS_DIR 1e-15f
#define EPS_W   1e-5f
#define NEAR_MIN 0.05f

// ---------------------------------------------------------------------------
// Specialized kernel for Tm1=127, n=128 (the benchmark shape).
//
// Decomposition: 8 lanes per ray (8 rays per wave, 32 rays per 256-thr block).
// Rationale (rounds 0-3 post-mortems): per-SAMPLE cost is lane-serial and
// invariant to the decomposition; per-RAY overhead (scan, near/far, setup)
// costs a full wave-inst each and is amortized by rays/wave. L=8 cuts it 8x
// vs wave-per-ray while keeping the memory pattern intact (which thread-per-
// ray destroyed: FETCH 79MB -> 1.5GB).
//  - 16 weights/lane in registers (statically indexed, full unroll)
//  - 3-step xor-butterfly scan over 8 lanes (prefix + total in one pass)
//  - per-ray 128-entry CDF in LDS at stride 132 floats (132 % 32 == 4:
//    de-aliases the 32 tables across banks; round-3 used stride 128 -> all
//    tables hit identical banks -> 8.7M conflict cycles)
//  - no __syncthreads: each ray's 8 lanes are in one wave; same-wave DS ops
//    are processed in order
//  - 16 samples/lane via 7-step binary search (uniform control flow),
//    4x float4 coalesced stores (512B contiguous per ray)
// ---------------------------------------------------------------------------
__global__ __launch_bounds__(256) void nerf_sample_pdf_127_128(
    const float* __restrict__ rays_o,
    const float* __restrict__ rays_d,
    const float* __restrict__ weights,
    const int*   __restrict__ bound_p,
    float*       __restrict__ out,
    int R)
{
    const int t    = threadIdx.x;
    const int g    = t & 7;            // lane within 8-lane ray group
    const int rloc = t >> 3;           // ray within block (0..31)
    int ray = blockIdx.x * 32 + rloc;
    const bool valid = (ray < R);
    if (!valid) ray = R - 1;           // clamp: loads safe, stores guarded

    __shared__ float cdf_s[32 * 132];  // 16.9 KB; 132-stride de-aliases banks
    float* __restrict__ cdf = cdf_s + rloc * 132;

    // ---- 16 weights per lane, kept in registers (static indexing) ----
    const float* __restrict__ wrow = weights + (size_t)ray * 127;
    const int i0 = g << 4;             // 16g
    float w[16];
#pragma unroll
    for (int k = 0; k < 16; ++k) {
        const int i = i0 + k;
        w[k] = (i < 127) ? (wrow[i] + EPS_W) : 0.0f;   // only g=7,k=15 masked
    }

    // serial local sum — same order as the cdf build below (consistency)
    float local = w[0];
#pragma unroll
    for (int k = 1; k < 16; ++k) local += w[k];

    // ---- 8-lane xor-butterfly: exclusive prefix + group total (3 steps) ----
    float prefix = 0.0f, val = local;
#pragma unroll
    for (int k = 1; k < 8; k <<= 1) {
        const float y = __shfl_xor(val, k, 8);
        if (g & k) prefix += y;
        val += y;                       // ends as group total in every lane
    }
    const float rtot = __builtin_amdgcn_rcpf(val);

    // ---- build cdf entries 16g+1 .. 16g+16 (entry 0 = 0 by lane 0) ----
    // g=7 writes entry 128 too (w[15]=0 -> duplicates entry 127; in-bounds,
    // makes the p+1 read safe even in the impossible u>=cdf[127] case).
    if (g == 0) cdf[0] = 0.0f;
    float run = prefix;
#pragma unroll
    for (int k = 0; k < 16; ++k) {
        run += w[k];
        cdf[i0 + k + 1] = run * rtot;   // max index 128 < 132: in-bounds
    }

    // ---- near/far cube intersection (8-lane redundant per ray) ----
    const float b = (float)bound_p[0];
    float nearv = -3.4e38f, farv = 3.4e38f;
#pragma unroll
    for (int k = 0; k < 3; ++k) {
        const float o = rays_o[(size_t)ray * 3 + k];
        const float d = rays_d[(size_t)ray * 3 + k] + EPS_DIR;
        const float r = __builtin_amdgcn_rcpf(d);
        const float t0 = (-b - o) * r;
        const float t1 = ( b - o) * r;
        nearv = fmaxf(nearv, fminf(t0, t1));
        farv  = fminf(farv,  fmaxf(t0, t1));
    }
    nearv = fmaxf(nearv, NEAR_MIN);
    const float scale = (farv - nearv) * (1.0f / 127.0f);

    // ---- 16 consecutive samples per lane: j = 16g + 0..15 ----
    // searchsorted(side='right'): p = largest e with cdf[e] <= u; a = p+1
    // (p <= 126 always since u_max = 0.99609 < cdf[127] ~= 1 - 1e-6).
    float* __restrict__ orow = out + (size_t)ray * 128;
    const float inv_n = 1.0f / 128.0f;

#pragma unroll
    for (int q = 0; q < 4; ++q) {
        float z0, z1, z2, z3;
#pragma unroll
        for (int s = 0; s < 4; ++s) {
            const int j = i0 + 4 * q + s;
            const float u = ((float)j + 0.5f) * inv_n;   // exact
            int p = 0; float v = 0.0f;
#pragma unroll
            for (int step = 64; step >= 1; step >>= 1) {
                const float c = cdf[p + step];           // p+step <= 127
                if (c <= u) { p += step; v = c; }
            }
            const float h   = cdf[p + 1];
            const float dnm = h - v;
            const float rd  = (dnm < EPS_W) ? 1.0f : __builtin_amdgcn_rcpf(dnm);
            const float tt  = (u - v) * rd;
            const float z   = fmaf((float)p + tt, scale, nearv);
            if      (s == 0) z0 = z;
            else if (s == 1) z1 = z;
            else if (s == 2) z2 = z;
            else             z3 = z;
        }
        if (valid) {
            *reinterpret_cast<float4*>(orow + i0 + 4 * q) =
                make_float4(z0, z1, z2, z3);             // 16B-aligned
        }
    }
}

// ---------------------------------------------------------------------------
// Generic fallback (round-3 kernel, verified correct): wave-per-ray gather.
// Used only if the shape is not (Tm1=127, n=128).
// ---------------------------------------------------------------------------
__global__ __launch_bounds__(256) void nerf_sample_pdf_generic(
    const float* __restrict__ rays_o,
    const float* __restrict__ rays_d,
    const float* __restrict__ weights,
    const int*   __restrict__ bound_p,
    float*       __restrict__ out,
    int R, int Tm1, int n)
{
    const int lane = threadIdx.x & 63;
    const int wid  = threadIdx.x >> 6;
    int ray = blockIdx.x * 4 + wid;
    const bool valid = (ray < R);
    if (!valid) ray = R - 1;

    __shared__ float cdf_s[4][132];
    float* __restrict__ cdf = cdf_s[wid];

    const float* __restrict__ wrow = weights + (size_t)ray * Tm1;
    const int i0 = 2 * lane, i1 = 2 * lane + 1;
    float w0 = (i0 < Tm1) ? (wrow[i0] + EPS_W) : 0.0f;
    float w1 = (i1 < Tm1) ? (wrow[i1] + EPS_W) : 0.0f;

    float S = w0 + w1;
#pragma unroll
    for (int off = 1; off < 64; off <<= 1) {
        float y = __shfl_up(S, off, 64);
        if (lane >= off) S += y;
    }
    const float total = __shfl(S, 63, 64);
    const float rinv  = __builtin_amdgcn_rcpf(total);
    float prevS = __shfl_up(S, 1, 64);
    if (lane == 0) prevS = 0.0f;

    cdf[i0] = prevS * rinv;
    cdf[i1] = (prevS + w0) * rinv;
    __syncthreads();

    const float b = (float)bound_p[0];
    float nearv = -3.4e38f, farv = 3.4e38f;
#pragma unroll
    for (int k = 0; k < 3; ++k) {
        float o = rays_o[(size_t)ray * 3 + k];
        float d = rays_d[(size_t)ray * 3 + k] + EPS_DIR;
        float r = __builtin_amdgcn_rcpf(d);
        float t0 = (-b - o) * r;
        float t1 = ( b - o) * r;
        nearv = fmaxf(nearv, fminf(t0, t1));
        farv  = fminf(farv,  fmaxf(t0, t1));
    }
    nearv = fmaxf(nearv, NEAR_MIN);
    const float scale = (farv - nearv) * __builtin_amdgcn_rcpf((float)Tm1);
    const float inv_n = 1.0f / (float)n;

    float* __restrict__ orow = out + (size_t)ray * n;

    for (int base = 0; base < n; base += 128) {
        const int j = base + 2 * lane;
        if (j >= n) break;
        const float u0 = ((float)j + 0.5f) * inv_n;
        const float u1 = u0 + inv_n;

        int   p0 = 0,   p1 = 0;
        float v0 = 0.f, v1 = 0.f;
#pragma unroll
        for (int step = 64; step >= 1; step >>= 1) {
            if (p0 + step <= Tm1) {
                const float c0 = cdf[p0 + step];
                if (c0 <= u0) { p0 += step; v0 = c0; }
            }
            if (p1 + step <= Tm1) {
                const float c1 = cdf[p1 + step];
                if (c1 <= u1) { p1 += step; v1 = c1; }
            }
        }
        const int a0 = (p0 < Tm1) ? p0 + 1 : Tm1;
        const int a1 = (p1 < Tm1) ? p1 + 1 : Tm1;
        const float h0 = cdf[a0];
        const float h1 = cdf[a1];
        const float d0 = h0 - v0;
        const float d1 = h1 - v1;
        const float t0 = (u0 - v0) * ((d0 < EPS_W) ? 1.0f : __builtin_amdgcn_rcpf(d0));
        const float t1 = (u1 - v1) * ((d1 < EPS_W) ? 1.0f : __builtin_amdgcn_rcpf(d1));
        const float z0 = fmaf(t0, (float)(a0 - p0) * scale, fmaf((float)p0, scale, nearv));
        const float z1 = fmaf(t1, (float)(a1 - p1) * scale, fmaf((float)p1, scale, nearv));

        if (valid) {
            if (j + 1 < n) {
                *reinterpret_cast<float2*>(orow + j) = make_float2(z0, z1);
            } else {
                orow[j] = z0;
            }
        }
    }
}

extern "C" void kernel_launch(void* const* d_in, const int* in_sizes, int n_in,
                              void* d_out, int out_size, void* d_ws, size_t ws_size,
                              hipStream_t stream) {
    const float* rays_o  = (const float*)d_in[0];
    const float* rays_d  = (const float*)d_in[1];
    const float* weights = (const float*)d_in[2];
    const int*   bound_p = (const int*)d_in[3];
    float*       out     = (float*)d_out;

    const int R   = in_sizes[0] / 3;       // 262144 rays
    const int Tm1 = in_sizes[2] / R;       // 127 weights per ray
    const int n   = out_size / R;          // 128 samples per ray

    if (Tm1 == 127 && n == 128) {
        dim3 grid((R + 31) / 32), block(256);   // 32 rays/block, 8 lanes/ray
        nerf_sample_pdf_127_128<<<grid, block, 0, stream>>>(
            rays_o, rays_d, weights, bound_p, out, R);
    } else {
        dim3 grid((R + 3) / 4), block(256);
        nerf_sample_pdf_generic<<<grid, block, 0, stream>>>(
            rays_o, rays_d, weights, bound_p, out, R, Tm1, n);
    }
}